// Round 9
// baseline (337.424 us; speedup 1.0000x reference)
//
#include <hip/hip_runtime.h>
#include <hip/hip_bf16.h>

#define B_TOT   16384
#define D_IN    784
#define H_DIM   100
#define C_DIM   10
#define HP      128
#define KP      832     // 13 * 64, padded K
#define NDR     13
#define WG_ROWS 32
#define WPR     49      // packed u32 words per row (784 / 16)
#define WPRP    52      // padded LDS row pitch in words
#define NW      (B_TOT * WPR)      // 802,816 words per timestep
#define NWORDS  (8 * NW)

typedef __bf16 bf16x8 __attribute__((ext_vector_type(8)));
typedef float  f32x4  __attribute__((ext_vector_type(4)));
typedef unsigned short u16x8 __attribute__((ext_vector_type(8)));

static __device__ __forceinline__ unsigned short f32_to_bf16(float f) {
    unsigned int u = __float_as_uint(f);
    unsigned int r = (u + 0x7FFFu + ((u >> 16) & 1u)) >> 16;
    return (unsigned short)r;
}

__global__ void prep_kernel(const float* __restrict__ W1, const float* __restrict__ b1,
                            unsigned short* __restrict__ w1hi, unsigned short* __restrict__ w1lo,
                            float* __restrict__ b1p) {
    int idx = blockIdx.x * 256 + threadIdx.x;
    if (idx < HP) b1p[idx] = (idx < H_DIM) ? b1[idx] : 0.0f;
    if (idx < HP * KP) {
        int h = idx / KP, k = idx - h * KP;
        float v = (h < H_DIM && k < D_IN) ? W1[h * D_IN + k] : 0.0f;
        unsigned short hi = f32_to_bf16(v);
        float fh = __uint_as_float(((unsigned int)hi) << 16);
        unsigned short lo = f32_to_bf16(v - fh);
        w1hi[idx] = hi;
        w1lo[idx] = lo;
    }
}

// ---------------- Phase A: pure-stream spike packing, inp read once ----------------
// word w covers flat elements [16w, 16w+16); bit 2e = fire, bit 2e+1 = negative.
// grid 3136 x 256 = exactly NW threads; all addresses flat-linear, no divisions.
__global__ __launch_bounds__(256)
void spike_pack(const float* __restrict__ inp, const float* __restrict__ rnd,
                unsigned* __restrict__ packed) {
    const size_t word = (size_t)blockIdx.x * 256 + threadIdx.x;   // < NW
    const f32x4* ip = reinterpret_cast<const f32x4*>(inp) + word * 4;
    f32x4 xs[4];
#pragma unroll
    for (int q = 0; q < 4; ++q) xs[q] = ip[q];

    float th[16];
    unsigned negmask = 0, nzmask = 0;
#pragma unroll
    for (int q = 0; q < 4; ++q)
#pragma unroll
        for (int j = 0; j < 4; ++j) {
            const int e = q * 4 + j;
            const float x = xs[q][j];
            th[e] = fabsf(x);
            negmask |= (x < 0.0f ? 1u : 0u) << (2 * e + 1);
            nzmask  |= (x != 0.0f ? 1u : 0u) << (2 * e);
        }

#pragma unroll
    for (int t = 0; t < 8; t += 2) {
        const f32x4* rpa = reinterpret_cast<const f32x4*>(rnd) + ((size_t)t * NW + word) * 4;
        const f32x4* rpb = rpa + (size_t)NW * 4;
        f32x4 ra[4], rb[4];
#pragma unroll
        for (int q = 0; q < 4; ++q) {
            ra[q] = __builtin_nontemporal_load(rpa + q);
            rb[q] = __builtin_nontemporal_load(rpb + q);
        }
        unsigned ca = 0, cb = 0;
#pragma unroll
        for (int q = 0; q < 4; ++q)
#pragma unroll
            for (int j = 0; j < 4; ++j) {
                const int e = q * 4 + j;
                ca |= (ra[q][j] * 2.0f <= th[e] ? 1u : 0u) << (2 * e);
                cb |= (rb[q][j] * 2.0f <= th[e] ? 1u : 0u) << (2 * e);
            }
        packed[(size_t)t * NW + word]       = (ca & nzmask) | negmask;
        packed[(size_t)(t + 1) * NW + word] = (cb & nzmask) | negmask;
    }
}

// ---------------- Phase B: barrier-free GEMM, in-register 2bit->bf16 unpack ----------------
__global__ __launch_bounds__(256, 2)
void snn_gemm(const unsigned* __restrict__ packed,
              const unsigned short* __restrict__ w1hi, const unsigned short* __restrict__ w1lo,
              const float* __restrict__ b1p, const float* __restrict__ W2,
              const float* __restrict__ b2, float* __restrict__ out)
{
    __shared__ unsigned s_packed[8 * WG_ROWS * WPRP];   // 53,248 B (rows padded to 52 words)
    __shared__ float s_cnt[WG_ROWS][HP];                // 16 KB

    const int tid  = threadIdx.x;
    const int lane = tid & 63;
    const int wid  = tid >> 6;          // 0..3
    const int m_off = (wid >> 1) * 16;
    const int n_off = (wid & 1) * 64;
    const int row0 = blockIdx.x * WG_ROWS;
    const int l15 = lane & 15;
    const int l4  = lane >> 4;

    // zero the 3-word pad of "my" (t,row) = tid
#pragma unroll
    for (int k = 0; k < 3; ++k) s_packed[tid * WPRP + WPR + k] = 0u;

    // stage all 8 timesteps' packed spikes (coalesced reads, padded LDS rows)
#pragma unroll
    for (int t = 0; t < 8; ++t) {
        const unsigned* src = packed + ((size_t)t * B_TOT + row0) * WPR;
#pragma unroll
        for (int i = 0; i < 7; ++i) {
            int w = tid + i * 256;
            if (w < WG_ROWS * WPR) {
                int r = w / WPR, g = w - r * WPR;
                s_packed[(t * WG_ROWS + r) * WPRP + g] = src[w];
            }
        }
    }

    float b1f[4];
#pragma unroll
    for (int nt = 0; nt < 4; ++nt) b1f[nt] = b1p[n_off + nt * 16 + l15];

    f32x4 mem1[4], cnt[4];
#pragma unroll
    for (int nt = 0; nt < 4; ++nt) { mem1[nt] = (f32x4)0.0f; cnt[nt] = (f32x4)0.0f; }

    __syncthreads();   // s_packed visible — the ONLY pre-epilogue barrier

    const char* spb = reinterpret_cast<const char*>(s_packed);
    const int rowA = m_off + l15;

    for (int tp = 0; tp < 2; ++tp) {
        f32x4 acc[4][4];   // [tt][nt]
#pragma unroll
        for (int a_ = 0; a_ < 4; ++a_)
#pragma unroll
            for (int b_ = 0; b_ < 4; ++b_) acc[a_][b_] = (f32x4)0.0f;

        for (int dr = 0; dr < NDR; ++dr) {
            const int kbase = dr * 64;
            bf16x8 bh[2][4], blo[2][4];
#pragma unroll
            for (int c = 0; c < 2; ++c)
#pragma unroll
                for (int nt = 0; nt < 4; ++nt) {
                    int off = (n_off + nt * 16 + l15) * KP + kbase + c * 32 + l4 * 8;
                    bh[c][nt]  = *reinterpret_cast<const bf16x8*>(w1hi + off);
                    blo[c][nt] = *reinterpret_cast<const bf16x8*>(w1lo + off);
                }

#pragma unroll
            for (int tt = 0; tt < 4; ++tt) {
                const int t = tp * 4 + tt;
                const int base = ((t * WG_ROWS + rowA) * WPRP) * 4 + dr * 16 + l4 * 2;
#pragma unroll
                for (int c = 0; c < 2; ++c) {
                    // 16 bits = this lane's 8 A-elements (2-bit codes); pad rows are zero
                    unsigned bits = *reinterpret_cast<const unsigned short*>(spb + base + c * 8);
                    union { unsigned u[4]; bf16x8 v; } cvt;
#pragma unroll
                    for (int p = 0; p < 4; ++p) {
                        unsigned n0 = (bits >> (4 * p)) & 3u;
                        unsigned n1 = (bits >> (4 * p + 2)) & 3u;
                        unsigned lo16 = (n0 & 1u) ? ((n0 & 2u) ? 0xBF80u : 0x3F80u) : 0u;
                        unsigned hi16 = (n1 & 1u) ? ((n1 & 2u) ? 0xBF80u : 0x3F80u) : 0u;
                        cvt.u[p] = lo16 | (hi16 << 16);
                    }
                    bf16x8 a = cvt.v;
#pragma unroll
                    for (int nt = 0; nt < 4; ++nt) {
                        acc[tt][nt] = __builtin_amdgcn_mfma_f32_16x16x32_bf16(a, bh[c][nt],  acc[tt][nt], 0, 0, 0);
                        acc[tt][nt] = __builtin_amdgcn_mfma_f32_16x16x32_bf16(a, blo[c][nt], acc[tt][nt], 0, 0, 0);
                    }
                }
            }
        }

        // sequential mem1 update for the 4 timesteps of this pass (order unchanged)
#pragma unroll
        for (int tt = 0; tt < 4; ++tt)
#pragma unroll
            for (int nt = 0; nt < 4; ++nt)
#pragma unroll
                for (int r = 0; r < 4; ++r) {
                    float m = 0.95f * mem1[nt][r] + acc[tt][nt][r];
                    m = m + b1f[nt];
                    float o = (m > 1.0f) ? 1.0f : 0.0f;
                    mem1[nt][r] = m - o;
                    cnt[nt][r] += o;
                }
    }

    // ---- epilogue: counts -> LDS -> layer-2 matmul ----
#pragma unroll
    for (int nt = 0; nt < 4; ++nt)
#pragma unroll
        for (int r = 0; r < 4; ++r)
            s_cnt[m_off + l4 * 4 + r][n_off + nt * 16 + l15] = cnt[nt][r];
    __syncthreads();
    for (int idx = tid; idx < WG_ROWS * C_DIM; idx += 256) {
        int bl_ = idx / C_DIM, c = idx - bl_ * C_DIM;
        float s = 0.0f;
        for (int h = 0; h < H_DIM; ++h) s += s_cnt[bl_][h] * W2[c * H_DIM + h];
        out[(size_t)(row0 + bl_) * C_DIM + c] = s * 0.125f + b2[c];
    }
}

// ---------------- fallback: verbatim round-1 fused kernel (used if ws too small) ----------------
__global__ __launch_bounds__(256, 2)
void snn_main(const float* __restrict__ inp, const float* __restrict__ rnd,
              const unsigned short* __restrict__ w1hi, const unsigned short* __restrict__ w1lo,
              const float* __restrict__ b1p, const float* __restrict__ W2,
              const float* __restrict__ b2, float* __restrict__ out)
{
    __shared__ __align__(16) unsigned short s_spike[WG_ROWS * 64];
    __shared__ float s_cnt[WG_ROWS][HP];

    const int tid  = threadIdx.x;
    const int lane = tid & 63;
    const int wid  = tid >> 6;
    const int m_off = (wid >> 1) * 16;
    const int n_off = (wid & 1) * 64;
    const int row0 = blockIdx.x * WG_ROWS;
    const int l15 = lane & 15;
    const int l4  = lane >> 4;

    float b1f[4];
#pragma unroll
    for (int nt = 0; nt < 4; ++nt) b1f[nt] = b1p[n_off + nt * 16 + l15];

    f32x4 mem1[4], cnt[4];
#pragma unroll
    for (int nt = 0; nt < 4; ++nt) { mem1[nt] = (f32x4)0.0f; cnt[nt] = (f32x4)0.0f; }

    const int sr  = tid >> 3;
    const int scg = tid & 7;
    const size_t inp_base = (size_t)(row0 + sr) * D_IN;
    const int swByte = (sr * 8 + (scg ^ (sr & 7))) * 16;

    for (int tp = 0; tp < 2; ++tp) {
        f32x4 acc[4][4];
#pragma unroll
        for (int a_ = 0; a_ < 4; ++a_)
#pragma unroll
            for (int b_ = 0; b_ < 4; ++b_) acc[a_][b_] = (f32x4)0.0f;

        for (int dr = 0; dr < NDR; ++dr) {
            const int kbase = dr * 64;
            bf16x8 bh[2][4], blo[2][4];
#pragma unroll
            for (int c = 0; c < 2; ++c)
#pragma unroll
                for (int nt = 0; nt < 4; ++nt) {
                    int off = (n_off + nt * 16 + l15) * KP + kbase + c * 32 + l4 * 8;
                    bh[c][nt]  = *reinterpret_cast<const bf16x8*>(w1hi + off);
                    blo[c][nt] = *reinterpret_cast<const bf16x8*>(w1lo + off);
                }
#pragma unroll
            for (int tt = 0; tt < 4; ++tt) {
                const int t = tp * 4 + tt;
                __syncthreads();
                {
                    const int gd = kbase + scg * 8;
                    u16x8 v = (u16x8)0;
                    if (gd + 8 <= D_IN) {
                        const f32x4* rp = reinterpret_cast<const f32x4*>(
                            rnd + (size_t)t * ((size_t)B_TOT * D_IN) + inp_base + gd);
                        const f32x4* ip = reinterpret_cast<const f32x4*>(inp + inp_base + gd);
                        f32x4 r0 = rp[0], r1 = rp[1];
                        f32x4 i0 = ip[0], i1 = ip[1];
                        float xsv[8] = {i0[0],i0[1],i0[2],i0[3],i1[0],i1[1],i1[2],i1[3]};
                        float rsv[8] = {r0[0],r0[1],r0[2],r0[3],r1[0],r1[1],r1[2],r1[3]};
#pragma unroll
                        for (int j = 0; j < 8; ++j) {
                            unsigned short sg = xsv[j] > 0.0f ? (unsigned short)0x3F80
                                              : (xsv[j] < 0.0f ? (unsigned short)0xBF80
                                                               : (unsigned short)0);
                            v[j] = (rsv[j] * 2.0f <= fabsf(xsv[j])) ? sg : (unsigned short)0;
                        }
                    }
                    *reinterpret_cast<u16x8*>(reinterpret_cast<char*>(s_spike) + swByte) = v;
                }
                __syncthreads();
#pragma unroll
                for (int c = 0; c < 2; ++c) {
                    const int rr = m_off + l15;
                    const int g = (c * 4 + l4) ^ (rr & 7);
                    bf16x8 a = *reinterpret_cast<const bf16x8*>(
                        reinterpret_cast<const char*>(s_spike) + rr * 128 + g * 16);
#pragma unroll
                    for (int nt = 0; nt < 4; ++nt) {
                        acc[tt][nt] = __builtin_amdgcn_mfma_f32_16x16x32_bf16(a, bh[c][nt],  acc[tt][nt], 0, 0, 0);
                        acc[tt][nt] = __builtin_amdgcn_mfma_f32_16x16x32_bf16(a, blo[c][nt], acc[tt][nt], 0, 0, 0);
                    }
                }
            }
        }
#pragma unroll
        for (int tt = 0; tt < 4; ++tt)
#pragma unroll
            for (int nt = 0; nt < 4; ++nt)
#pragma unroll
                for (int r = 0; r < 4; ++r) {
                    float m = 0.95f * mem1[nt][r] + acc[tt][nt][r];
                    m = m + b1f[nt];
                    float o = (m > 1.0f) ? 1.0f : 0.0f;
                    mem1[nt][r] = m - o;
                    cnt[nt][r] += o;
                }
    }

    __syncthreads();
#pragma unroll
    for (int nt = 0; nt < 4; ++nt)
#pragma unroll
        for (int r = 0; r < 4; ++r)
            s_cnt[m_off + l4 * 4 + r][n_off + nt * 16 + l15] = cnt[nt][r];
    __syncthreads();
    for (int idx = tid; idx < WG_ROWS * C_DIM; idx += 256) {
        int bl_ = idx / C_DIM, c = idx - bl_ * C_DIM;
        float s = 0.0f;
        for (int h = 0; h < H_DIM; ++h) s += s_cnt[bl_][h] * W2[c * H_DIM + h];
        out[(size_t)(row0 + bl_) * C_DIM + c] = s * 0.125f + b2[c];
    }
}

extern "C" void kernel_launch(void* const* d_in, const int* in_sizes, int n_in,
                              void* d_out, int out_size, void* d_ws, size_t ws_size,
                              hipStream_t stream) {
    const float* inp = (const float*)d_in[0];
    const float* rnd = (const float*)d_in[1];
    const float* W1  = (const float*)d_in[2];
    const float* b1  = (const float*)d_in[3];
    const float* W2  = (const float*)d_in[4];
    const float* b2  = (const float*)d_in[5];
    float* out = (float*)d_out;

    unsigned short* w1hi = (unsigned short*)d_ws;
    unsigned short* w1lo = w1hi + HP * KP;
    float* b1p = (float*)(w1lo + HP * KP);
    unsigned* packed = (unsigned*)(b1p + HP);   // offset 426,496 B

    const size_t needed = 426496 + (size_t)NWORDS * 4;

    prep_kernel<<<(HP * KP + 255) / 256, 256, 0, stream>>>(W1, b1, w1hi, w1lo, b1p);

    if (ws_size >= needed) {
        spike_pack<<<NW / 256, 256, 0, stream>>>(inp, rnd, packed);
        snn_gemm<<<B_TOT / WG_ROWS, 256, 0, stream>>>(packed, w1hi, w1lo, b1p, W2, b2, out);
    } else {
        snn_main<<<B_TOT / WG_ROWS, 256, 0, stream>>>(inp, rnd, w1hi, w1lo, b1p, W2, b2, out);
    }
}